// Round 3
// baseline (143.052 us; speedup 1.0000x reference)
//
#include <hip/hip_runtime.h>
#include <cstdint>

#define T_DIM 1000
#define B_DIM 64
#define C_DIM 256
#define L_DIM 100
#define S_DIM (2 * L_DIM + 1) /* 201 */
#define CH 32                 /* steps per chunk */
#define NPROD 7               /* producer waves (block = 8 waves) */
#define RPW 5                 /* ceil(CH/NPROD) rows per producer wave */
#define EMW 132               /* emit row stride: 64 q1 + 64 q3 + pb + 3 pad */
#define MEAN_BLOCKS 256       /* 64 b x 4 ; each block covers 2 of 8 T-slices */
#define MEAN_ROWS 125

// DPP cross-lane (VALU-rate). wave_shr:1=0x138, row_shr:n=0x110|n,
// row_bcast:15=0x142, row_bcast:31=0x143. bound_ctrl=true -> invalid lanes read 0.
#define DPP_I(x, ctrl) __builtin_amdgcn_update_dpp(0, (x), (ctrl), 0xF, 0xF, true)
#define DPP_F(x, ctrl) __int_as_float(DPP_I(__float_as_int(x), (ctrl)))

// Empty inline-asm pin (producer only): forces global loads to stay hoisted
// above the store loop (stops remat-sink). NOTE R1 lesson: PIN does NOT
// create prefetch distance on the consumer -- each load just sinks to its
// own PIN. Consumer now uses data-dependence-ordered rotation instead.
#define PIN(x) asm volatile("" : "+v"(x))

// Wave-wide max of non-negative values; exact, order-independent.
__device__ __forceinline__ float wave_max_dpp(float x) {
    x = fmaxf(x, DPP_F(x, 0x111)); // row_shr:1
    x = fmaxf(x, DPP_F(x, 0x112)); // row_shr:2
    x = fmaxf(x, DPP_F(x, 0x114)); // row_shr:4
    x = fmaxf(x, DPP_F(x, 0x118)); // row_shr:8
    x = fmaxf(x, DPP_F(x, 0x142)); // row_bcast:15
    x = fmaxf(x, DPP_F(x, 0x143)); // row_bcast:31 -> lane 63 has wave max
    return __int_as_float(__builtin_amdgcn_readlane(__float_as_int(x), 63));
}

// Fused kernel, 512-thread blocks:
//   blocks [0,B): CTC alpha recursion.
//     R2 restructure: the consumer's per-step 64-lane random gathers
//     (rows[d][c1], rows[d][c3] -- 474k measured conflict cycles, plus
//     ~64-120cy exposed ds_read latency per serial step) are moved to the
//     PRODUCERS: they stage the raw row in private scratch, gather the 129
//     needed values (c1/c3 are per-lane constants, same every step), exp
//     only those, and write a compact conflict-free emit row:
//     [lane]=q1, [64+lane]=q3, [128]=pb. Consumer reads are now stride-4B
//     lane-linear (2 lanes/bank = free) + 1 broadcast, depth-2 pipelined.
//   blocks [B, B+256): mean-over-time exp(log_probs) -> atomicAdd ws_mean.
__global__ __launch_bounds__(512, 1) void ctc_fused(
        const float* __restrict__ lp,       // (T,B,C)
        const int* __restrict__ tgt,        // (B*L,)
        const int* __restrict__ il,         // (B,)
        const int* __restrict__ tl,         // (B,)
        float* __restrict__ ws_mean,        // (B,C) zero-initialized
        float* __restrict__ ws_loss) {      // (B,)
    const int blk = blockIdx.x;
    const uint32_t rstride = B_DIM * C_DIM;

    if (blk >= B_DIM) {
        // ---- mean_probs pass: block = (b, slicepair); thread = (half, c) ----
        const int mb = blk - B_DIM;
        const int b = mb >> 2;
        const int half = threadIdx.x >> 8;         // 0/1
        const int c = threadIdx.x & 255;
        const int slice = ((mb & 3) << 1) + half;  // 0..7, 125 rows each
        const float* p = lp + (size_t)b * C_DIM + c + (size_t)(slice * MEAN_ROWS) * rstride;
        float s0 = 0.f, s1 = 0.f, s2 = 0.f, s3 = 0.f, s4 = 0.f;
        for (int t = 0; t < MEAN_ROWS; t += 5) {
            s0 += __expf(p[(size_t)(t + 0) * rstride]);
            s1 += __expf(p[(size_t)(t + 1) * rstride]);
            s2 += __expf(p[(size_t)(t + 2) * rstride]);
            s3 += __expf(p[(size_t)(t + 3) * rstride]);
            s4 += __expf(p[(size_t)(t + 4) * rstride]);
        }
        atomicAdd(&ws_mean[b * C_DIM + c], (s0 + s1 + s2 + s3 + s4) * (1.0f / T_DIM));
        return;
    }

    // ---- CTC pass ----
    __shared__ __align__(16) float scratch[NPROD][RPW][C_DIM]; // raw rows, 35 KB
    __shared__ __align__(16) float emit[2][CH][EMW];           // compact exp'd, 33 KB

    const int tid = threadIdx.x;
    const int lane = tid & 63;
    const int wave = tid >> 6;
    const int b = blk;
    const int* trow = tgt + b * L_DIM;
    const int ilen = il[b];
    const int tlen = tl[b];

    const int i1 = 2 * lane;
    const int i3 = 2 * lane + 1;
    const int c1 = (i1 < L_DIM) ? trow[i1] : 0;
    const int c3 = (i3 < L_DIM) ? trow[i3] : 0;
    const int c1m = (i1 >= 1 && i1 - 1 < L_DIM) ? trow[i1 - 1] : -1;
    const float m1 = ((i1 >= 1) && (c1 != c1m)) ? 1.0f : 0.0f;
    const float m3 = (c3 != c1) ? 1.0f : 0.0f;

    // invalid states (s >= S) must be zeroed at each renorm (R2 lesson)
    const float f0 = (4 * lane + 0 < S_DIM) ? 1.0f : 0.0f;
    const float f1 = (4 * lane + 1 < S_DIM) ? 1.0f : 0.0f;
    const float f2 = (4 * lane + 2 < S_DIM) ? 1.0f : 0.0f;
    const float f3 = (4 * lane + 3 < S_DIM) ? 1.0f : 0.0f;

    const float* base = lp + (size_t)b * C_DIM;

    // t=0 init (bit-identical to R5..R9)
    float a0 = 0.f, a1 = 0.f, a2 = 0.f, a3 = 0.f;
    {
        float i0 = __expf(base[0]);
        float i1v = __expf(base[c1]);
        if (lane == 0 && wave == 0) { a0 = i0; a1 = i1v; }
    }
    float ls = 0.f;

    // producer: coalesced row loads -> raw scratch -> gather 2 values/lane
    // (conflicts now OFF the serial chain) -> exp only what's consumed ->
    // compact conflict-free emit row. pb comes straight from lane0's v[k].x.
    auto produce = [&](int cc) {
        const int p = cc & 1;
        const int tstart = 1 + cc * CH;
        const int w = wave - 1;
        float4 v[RPW];
#pragma unroll
        for (int k = 0; k < RPW; ++k) {
            const int d = w + NPROD * k;
            if (d < CH) {
                int t = tstart + d; t = (t < ilen) ? t : (ilen - 1);
                v[k] = *(const float4*)(base + (size_t)t * rstride + (lane << 2));
            }
        }
#pragma unroll
        for (int k = 0; k < RPW; ++k) {
            const int d = w + NPROD * k;
            if (d < CH) { PIN(v[k].x); PIN(v[k].y); PIN(v[k].z); PIN(v[k].w); }
        }
#pragma unroll
        for (int k = 0; k < RPW; ++k) {
            const int d = w + NPROD * k;
            if (d < CH) *(float4*)&scratch[w][k][lane << 2] = v[k];
        }
#pragma unroll
        for (int k = 0; k < RPW; ++k) {
            const int d = w + NPROD * k;
            if (d < CH) {
                const float g1 = scratch[w][k][c1];
                const float g3 = scratch[w][k][c3];
                emit[p][d][lane] = __expf(g1);
                emit[p][d][64 + lane] = __expf(g3);
                if (lane == 0) emit[p][d][128] = __expf(v[k].x);
            }
        }
    };

    // consumer step: inputs are already exp'd (bitwise-identical to computing
    // __expf locally -- same v_exp_f32 on same inputs). absmax must stay 96.0.
    auto step = [&](float pb, float p1e, float p3e) {
        const float p3 = DPP_F(a3, 0x138); // prev lane's a3; lane0 -> 0
        const float a01 = a0 + a1;
        const float n0 = (a0 + p3) * pb;
        const float n1 = fmaf(m1, p3, a01) * p1e;
        const float n2 = (a2 + a1) * pb;
        const float n3 = (fmaf(m3, a1, a2) + a3) * p3e;
        a0 = n0; a1 = n1; a2 = n2; a3 = n3;
    };

#define RENORM() do {                                                       \
        a0 *= f0; a1 *= f1; a2 *= f2; a3 *= f3;                             \
        const float mx = wave_max_dpp(fmaxf(fmaxf(a0, a1), fmaxf(a2, a3))); \
        const float inv = __builtin_amdgcn_rcpf(mx);                        \
        ls -= __logf(inv);                                                  \
        a0 *= inv; a1 *= inv; a2 *= inv; a3 *= inv;                         \
    } while (0)

    // consume chunk cc; renorms at d&7==7 -> t = 8,16,24,32 (mod 32) == all
    // t%8==0 in range: EXACTLY R5/R9's renorm set (last at t=992 for T=1000).
    // Depth-2 software pipeline with NAMED registers (static indices, fully
    // unrolled): read(d+2) precedes use(d) in dependence order, so the
    // compiler cannot collapse the prefetch (R1 lesson: PIN couldn't do this).
    auto consume = [&](int cc) {
        const int p = cc & 1;
        const int tstart = 1 + cc * CH;
        if (tstart + CH <= ilen) {
            float pbA = emit[p][0][128], q1A = emit[p][0][lane], q3A = emit[p][0][64 + lane];
            float pbB = emit[p][1][128], q1B = emit[p][1][lane], q3B = emit[p][1][64 + lane];
#pragma unroll
            for (int d = 0; d < CH; ++d) {
                float pbN, q1N, q3N;
                if (d + 2 < CH) {
                    pbN = emit[p][d + 2][128];
                    q1N = emit[p][d + 2][lane];
                    q3N = emit[p][d + 2][64 + lane];
                }
                step(pbA, q1A, q3A);
                if ((d & 7) == 7) RENORM();
                pbA = pbB; q1A = q1B; q3A = q3B;
                if (d + 2 < CH) { pbB = pbN; q1B = q1N; q3B = q3N; }
            }
        } else {
#pragma unroll
            for (int d = 0; d < CH; ++d) {
                if (tstart + d < ilen) {
                    step(emit[p][d][128], emit[p][d][lane], emit[p][d][64 + lane]);
                    if ((d & 7) == 7) RENORM();
                }
            }
        }
    };

    const int nchunks = (ilen - 1 + CH - 1) / CH;
    if (wave != 0) produce(0);
    __syncthreads();
    for (int c = 0; c < nchunks; ++c) {
        if (wave != 0) produce(c + 1); // other parity; last iter clamped junk, never read
        else consume(c);
        __syncthreads();
    }
#undef RENORM

    if (wave != 0) return;

    // final: ll = log(alpha[2tl] + alpha[2tl-1]) + ls   (consumer wave only)
    const int s_hi = 2 * tlen;
    const int s_lo = 2 * tlen - 1;
    const int slot_hi = s_hi & 3, lane_hi = min(s_hi >> 2, 63);
    const int slot_lo = s_lo & 3, lane_lo = min(s_lo >> 2, 63);
    float ch = (slot_hi == 0) ? a0 : (slot_hi == 1) ? a1 : (slot_hi == 2) ? a2 : a3;
    float cl = (slot_lo == 0) ? a0 : (slot_lo == 1) ? a1 : (slot_lo == 2) ? a2 : a3;
    const float vh = __shfl(ch, lane_hi, 64);
    const float vl = __shfl(cl, lane_lo, 64);
    if (lane == 0) {
        const float s = vh + vl;
        const float loss = (s > 0.f) ? -(__logf(s) + ls) : 0.0f; // zero_infinity
        ws_loss[b] = loss;
    }
}

// out = (sum_j focal_j / (B*L)) * (sum_b loss_b / B)
__global__ __launch_bounds__(256) void ctc_finalize(
        const float* __restrict__ ws_mean, const float* __restrict__ ws_loss,
        const int* __restrict__ tgt, float* __restrict__ out) {
    const int tid = threadIdx.x;
    float fsum = 0.f;
#pragma unroll
    for (int k = 0; k < (B_DIM * L_DIM) / 256; ++k) {
        const int j = tid + k * 256;
        const int b = j / L_DIM;
        const int c = tgt[j];
        const float p = ws_mean[b * C_DIM + c];
        const float w = 1.0f - p;
        fsum += w * w;
    }
    float lsum = (tid < B_DIM) ? ws_loss[tid] : 0.f;
#pragma unroll
    for (int off = 32; off > 0; off >>= 1) {
        fsum += __shfl_down(fsum, off, 64);
        lsum += __shfl_down(lsum, off, 64);
    }
    __shared__ float sf[4], sl[4];
    const int w = tid >> 6;
    if ((tid & 63) == 0) { sf[w] = fsum; sl[w] = lsum; }
    __syncthreads();
    if (tid == 0) {
        const float F = sf[0] + sf[1] + sf[2] + sf[3];
        const float Lo = sl[0] + sl[1] + sl[2] + sl[3];
        out[0] = (F / (float)(B_DIM * L_DIM)) * (Lo / (float)B_DIM);
    }
}

extern "C" void kernel_launch(void* const* d_in, const int* in_sizes, int n_in,
                              void* d_out, int out_size, void* d_ws, size_t ws_size,
                              hipStream_t stream) {
    const float* lp = (const float*)d_in[0];
    const int* tgt = (const int*)d_in[1];
    const int* il = (const int*)d_in[2];
    const int* tl = (const int*)d_in[3];
    float* ws_mean = (float*)d_ws;               // B*C floats (atomicAdd target)
    float* ws_loss = ws_mean + B_DIM * C_DIM;    // B floats

    hipMemsetAsync(ws_mean, 0, B_DIM * C_DIM * sizeof(float), stream);
    ctc_fused<<<dim3(B_DIM + MEAN_BLOCKS), dim3(512), 0, stream>>>(
        lp, tgt, il, tl, ws_mean, ws_loss);
    ctc_finalize<<<dim3(1), dim3(256), 0, stream>>>(ws_mean, ws_loss, tgt, (float*)d_out);
}

// Round 4
// 139.159 us; speedup vs baseline: 1.0280x; 1.0280x over previous
//
#include <hip/hip_runtime.h>
#include <cstdint>

#define T_DIM 1000
#define B_DIM 64
#define C_DIM 256
#define L_DIM 100
#define S_DIM (2 * L_DIM + 1) /* 201 */
#define CH 32                 /* steps per chunk */
#define NPROD 7               /* producer waves (block = 8 waves) */
#define RPW 5                 /* ceil(CH/NPROD) rows per producer wave */
#define MEAN_BLOCKS 256       /* 64 b x 4 ; each block covers 2 of 8 T-slices */
#define MEAN_ROWS 125

// DPP cross-lane (VALU-rate). wave_shr:1=0x138, row_shr:n=0x110|n,
// row_bcast:15=0x142, row_bcast:31=0x143. bound_ctrl=true -> invalid lanes read 0.
#define DPP_I(x, ctrl) __builtin_amdgcn_update_dpp(0, (x), (ctrl), 0xF, 0xF, true)
#define DPP_F(x, ctrl) __int_as_float(DPP_I(__float_as_int(x), (ctrl)))

// Empty inline-asm pin (producer only): forces global loads to stay hoisted
// above the store loop. R1/R2 lesson: PIN and dataflow rotation do NOT stop
// the scheduler sinking ds_read to point-of-use on the consumer; only
// sched_group_barrier does (R3).
#define PIN(x) asm volatile("" : "+v"(x))

// Wave-wide max of non-negative values; exact, order-independent.
__device__ __forceinline__ float wave_max_dpp(float x) {
    x = fmaxf(x, DPP_F(x, 0x111)); // row_shr:1
    x = fmaxf(x, DPP_F(x, 0x112)); // row_shr:2
    x = fmaxf(x, DPP_F(x, 0x114)); // row_shr:4
    x = fmaxf(x, DPP_F(x, 0x118)); // row_shr:8
    x = fmaxf(x, DPP_F(x, 0x142)); // row_bcast:15
    x = fmaxf(x, DPP_F(x, 0x143)); // row_bcast:31 -> lane 63 has wave max
    return __int_as_float(__builtin_amdgcn_readlane(__float_as_int(x), 63));
}

// Fused kernel, 512-thread blocks:
//   blocks [0,B): CTC alpha recursion.
//     wave 0  = consumer: serial chain. R3: depth-3 software pipeline over
//               groups of 2 steps; each group's 6 ds_reads are pinned ~3
//               groups ahead of use via __builtin_amdgcn_sched_group_barrier
//               (DS_READ mask 0x100). Loads stay compiler-visible, so the
//               waitcnt pass emits counted lgkmcnt automatically. This is
//               the only mechanism that survives the scheduler's
//               sink-to-use (PIN failed R1, rotation failed R2).
//               s_setprio(1): consumer wins issue arbitration vs producers
//               (role-split exists, T5 prerequisite).
//     waves 1-7 = producers: per chunk, each loads 5 full rows COALESCED
//               (one global_load_dwordx4 per row), pins them, applies __expf
//               to the whole row, stores to ping-pong LDS. (Baseline form --
//               R2's producer-side gather round-trip reverted.)
//   blocks [B, B+256): mean-over-time exp(log_probs) -> atomicAdd ws_mean.
__global__ __launch_bounds__(512, 1) void ctc_fused(
        const float* __restrict__ lp,       // (T,B,C)
        const int* __restrict__ tgt,        // (B*L,)
        const int* __restrict__ il,         // (B,)
        const int* __restrict__ tl,         // (B,)
        float* __restrict__ ws_mean,        // (B,C) zero-initialized
        float* __restrict__ ws_loss) {      // (B,)
    const int blk = blockIdx.x;
    const uint32_t rstride = B_DIM * C_DIM;

    if (blk >= B_DIM) {
        // ---- mean_probs pass: block = (b, slicepair); thread = (half, c) ----
        const int mb = blk - B_DIM;
        const int b = mb >> 2;
        const int half = threadIdx.x >> 8;         // 0/1
        const int c = threadIdx.x & 255;
        const int slice = ((mb & 3) << 1) + half;  // 0..7, 125 rows each
        const float* p = lp + (size_t)b * C_DIM + c + (size_t)(slice * MEAN_ROWS) * rstride;
        float s0 = 0.f, s1 = 0.f, s2 = 0.f, s3 = 0.f, s4 = 0.f;
        for (int t = 0; t < MEAN_ROWS; t += 5) {
            s0 += __expf(p[(size_t)(t + 0) * rstride]);
            s1 += __expf(p[(size_t)(t + 1) * rstride]);
            s2 += __expf(p[(size_t)(t + 2) * rstride]);
            s3 += __expf(p[(size_t)(t + 3) * rstride]);
            s4 += __expf(p[(size_t)(t + 4) * rstride]);
        }
        atomicAdd(&ws_mean[b * C_DIM + c], (s0 + s1 + s2 + s3 + s4) * (1.0f / T_DIM));
        return;
    }

    // ---- CTC pass ----
    __shared__ __align__(16) float rows[2][CH][C_DIM]; // exp'd rows, 64 KB

    const int tid = threadIdx.x;
    const int lane = tid & 63;
    const int wave = tid >> 6;
    const int b = blk;
    const int* trow = tgt + b * L_DIM;
    const int ilen = il[b];
    const int tlen = tl[b];

    const int i1 = 2 * lane;
    const int i3 = 2 * lane + 1;
    const int c1 = (i1 < L_DIM) ? trow[i1] : 0;
    const int c3 = (i3 < L_DIM) ? trow[i3] : 0;
    const int c1m = (i1 >= 1 && i1 - 1 < L_DIM) ? trow[i1 - 1] : -1;
    const float m1 = ((i1 >= 1) && (c1 != c1m)) ? 1.0f : 0.0f;
    const float m3 = (c3 != c1) ? 1.0f : 0.0f;

    // invalid states (s >= S) must be zeroed at each renorm (R2 lesson)
    const float f0 = (4 * lane + 0 < S_DIM) ? 1.0f : 0.0f;
    const float f1 = (4 * lane + 1 < S_DIM) ? 1.0f : 0.0f;
    const float f2 = (4 * lane + 2 < S_DIM) ? 1.0f : 0.0f;
    const float f3 = (4 * lane + 3 < S_DIM) ? 1.0f : 0.0f;

    const float* base = lp + (size_t)b * C_DIM;

    // t=0 init (bit-identical to R5..R9)
    float a0 = 0.f, a1 = 0.f, a2 = 0.f, a3 = 0.f;
    {
        float i0 = __expf(base[0]);
        float i1v = __expf(base[c1]);
        if (lane == 0 && wave == 0) { a0 = i0; a1 = i1v; }
    }
    float ls = 0.f;

    // producer: 5 coalesced row loads (phase 1), pin, exp + LDS store (phase 2)
    auto produce = [&](int cc) {
        const int p = cc & 1;
        const int tstart = 1 + cc * CH;
        float4 v[RPW];
#pragma unroll
        for (int k = 0; k < RPW; ++k) {
            const int d = (wave - 1) + NPROD * k;
            if (d < CH) {
                int t = tstart + d; t = (t < ilen) ? t : (ilen - 1);
                v[k] = *(const float4*)(base + (size_t)t * rstride + (lane << 2));
            }
        }
#pragma unroll
        for (int k = 0; k < RPW; ++k) {
            const int d = (wave - 1) + NPROD * k;
            if (d < CH) { PIN(v[k].x); PIN(v[k].y); PIN(v[k].z); PIN(v[k].w); }
        }
#pragma unroll
        for (int k = 0; k < RPW; ++k) {
            const int d = (wave - 1) + NPROD * k;
            if (d < CH) {
                float4 e;
                e.x = __expf(v[k].x); e.y = __expf(v[k].y);
                e.z = __expf(v[k].z); e.w = __expf(v[k].w);
                *(float4*)&rows[p][d][lane << 2] = e;
            }
        }
    };

    // consumer step: inputs are already exp'd (bitwise-identical to computing
    // __expf locally -- same v_exp_f32 on same inputs). absmax must stay 96.0.
    auto step = [&](float pb, float p1e, float p3e) {
        const float p3 = DPP_F(a3, 0x138); // prev lane's a3; lane0 -> 0
        const float a01 = a0 + a1;
        const float n0 = (a0 + p3) * pb;
        const float n1 = fmaf(m1, p3, a01) * p1e;
        const float n2 = (a2 + a1) * pb;
        const float n3 = (fmaf(m3, a1, a2) + a3) * p3e;
        a0 = n0; a1 = n1; a2 = n2; a3 = n3;
    };

#define RENORM() do {                                                       \
        a0 *= f0; a1 *= f1; a2 *= f2; a3 *= f3;                             \
        const float mx = wave_max_dpp(fmaxf(fmaxf(a0, a1), fmaxf(a2, a3))); \
        const float inv = __builtin_amdgcn_rcpf(mx);                        \
        ls -= __logf(inv);                                                  \
        a0 *= inv; a1 *= inv; a2 *= inv; a3 *= inv;                         \
    } while (0)

    // consume chunk cc; renorms after d=7,15,23,31 (g&3==3): EXACTLY the
    // baseline renorm set (last at t=992 for T=1000). Steady path: depth-3
    // rotation over 2-step groups (18 named floats, static indices only).
    // SGB(0x100 = DS_READ, n) pins each group's reads n-deep ahead of use;
    // the compiler's waitcnt pass then emits counted lgkmcnt. Max in-flight
    // DS = 12-18 (lgkmcnt cap 15 -> worst case a 3-deep issue stall on
    // already-old reads, negligible).
    auto consume = [&](int cc) {
        const int p = cc & 1;
        const int tstart = 1 + cc * CH;
        if (tstart + CH <= ilen) {
            float Ab0 = rows[p][0][0], A10 = rows[p][0][c1], A30 = rows[p][0][c3];
            float Ab1 = rows[p][1][0], A11 = rows[p][1][c1], A31 = rows[p][1][c3];
            float Bb0 = rows[p][2][0], B10 = rows[p][2][c1], B30 = rows[p][2][c3];
            float Bb1 = rows[p][3][0], B11 = rows[p][3][c1], B31 = rows[p][3][c3];
            float Cb0 = rows[p][4][0], C10 = rows[p][4][c1], C30 = rows[p][4][c3];
            float Cb1 = rows[p][5][0], C11 = rows[p][5][c1], C31 = rows[p][5][c3];
            __builtin_amdgcn_sched_group_barrier(0x100, 18, 0); // prologue reads stay up top
#pragma unroll
            for (int g = 0; g < CH / 2; ++g) {
                step(Ab0, A10, A30);             // d = 2g
                step(Ab1, A11, A31);             // d = 2g+1
                if ((g & 3) == 3) RENORM();      // == (d&7)==7
                Ab0 = Bb0; A10 = B10; A30 = B30; Ab1 = Bb1; A11 = B11; A31 = B31;
                Bb0 = Cb0; B10 = C10; B30 = C30; Bb1 = Cb1; B11 = C11; B31 = C31;
                if (g + 3 < CH / 2) {
                    const int d = 2 * (g + 3);
                    Cb0 = rows[p][d][0];     C10 = rows[p][d][c1];     C30 = rows[p][d][c3];
                    Cb1 = rows[p][d + 1][0]; C11 = rows[p][d + 1][c1]; C31 = rows[p][d + 1][c3];
                    __builtin_amdgcn_sched_group_barrier(0x100, 6, 0); // pin these 6 here
                }
            }
        } else {
            // tail chunk (7 steps for T=1000): baseline point-of-use form
#pragma unroll
            for (int d = 0; d < CH; ++d) {
                if (tstart + d < ilen) {
                    step(rows[p][d][0], rows[p][d][c1], rows[p][d][c3]);
                    if ((d & 7) == 7) RENORM();
                }
            }
        }
    };

    const int nchunks = (ilen - 1 + CH - 1) / CH;
    if (wave != 0) produce(0);
    __syncthreads();
    if (wave == 0) __builtin_amdgcn_s_setprio(1); // consumer is the critical chain
    for (int c = 0; c < nchunks; ++c) {
        if (wave != 0) produce(c + 1); // other parity; last iter clamped junk, never read
        else consume(c);
        __syncthreads();
    }
    if (wave == 0) __builtin_amdgcn_s_setprio(0);
#undef RENORM

    if (wave != 0) return;

    // final: ll = log(alpha[2tl] + alpha[2tl-1]) + ls   (consumer wave only)
    const int s_hi = 2 * tlen;
    const int s_lo = 2 * tlen - 1;
    const int slot_hi = s_hi & 3, lane_hi = min(s_hi >> 2, 63);
    const int slot_lo = s_lo & 3, lane_lo = min(s_lo >> 2, 63);
    float ch = (slot_hi == 0) ? a0 : (slot_hi == 1) ? a1 : (slot_hi == 2) ? a2 : a3;
    float cl = (slot_lo == 0) ? a0 : (slot_lo == 1) ? a1 : (slot_lo == 2) ? a2 : a3;
    const float vh = __shfl(ch, lane_hi, 64);
    const float vl = __shfl(cl, lane_lo, 64);
    if (lane == 0) {
        const float s = vh + vl;
        const float loss = (s > 0.f) ? -(__logf(s) + ls) : 0.0f; // zero_infinity
        ws_loss[b] = loss;
    }
}

// out = (sum_j focal_j / (B*L)) * (sum_b loss_b / B)
__global__ __launch_bounds__(256) void ctc_finalize(
        const float* __restrict__ ws_mean, const float* __restrict__ ws_loss,
        const int* __restrict__ tgt, float* __restrict__ out) {
    const int tid = threadIdx.x;
    float fsum = 0.f;
#pragma unroll
    for (int k = 0; k < (B_DIM * L_DIM) / 256; ++k) {
        const int j = tid + k * 256;
        const int b = j / L_DIM;
        const int c = tgt[j];
        const float p = ws_mean[b * C_DIM + c];
        const float w = 1.0f - p;
        fsum += w * w;
    }
    float lsum = (tid < B_DIM) ? ws_loss[tid] : 0.f;
#pragma unroll
    for (int off = 32; off > 0; off >>= 1) {
        fsum += __shfl_down(fsum, off, 64);
        lsum += __shfl_down(lsum, off, 64);
    }
    __shared__ float sf[4], sl[4];
    const int w = tid >> 6;
    if ((tid & 63) == 0) { sf[w] = fsum; sl[w] = lsum; }
    __syncthreads();
    if (tid == 0) {
        const float F = sf[0] + sf[1] + sf[2] + sf[3];
        const float Lo = sl[0] + sl[1] + sl[2] + sl[3];
        out[0] = (F / (float)(B_DIM * L_DIM)) * (Lo / (float)B_DIM);
    }
}

extern "C" void kernel_launch(void* const* d_in, const int* in_sizes, int n_in,
                              void* d_out, int out_size, void* d_ws, size_t ws_size,
                              hipStream_t stream) {
    const float* lp = (const float*)d_in[0];
    const int* tgt = (const int*)d_in[1];
    const int* il = (const int*)d_in[2];
    const int* tl = (const int*)d_in[3];
    float* ws_mean = (float*)d_ws;               // B*C floats (atomicAdd target)
    float* ws_loss = ws_mean + B_DIM * C_DIM;    // B floats

    hipMemsetAsync(ws_mean, 0, B_DIM * C_DIM * sizeof(float), stream);
    ctc_fused<<<dim3(B_DIM + MEAN_BLOCKS), dim3(512), 0, stream>>>(
        lp, tgt, il, tl, ws_mean, ws_loss);
    ctc_finalize<<<dim3(1), dim3(256), 0, stream>>>(ws_mean, ws_loss, tgt, (float*)d_out);
}